// Round 4
// baseline (228.152 us; speedup 1.0000x reference)
//
#include <hip/hip_runtime.h>
#include <hip/hip_bf16.h>

#define TOK   16384       // B*N = 4*4096
#define KD    1024        // DIM
#define NQKV  3072
#define SEQL  4096
#define ATT_SCALE 0.125f  // 64^-0.5

typedef __attribute__((ext_vector_type(4))) float f32x4;
typedef __attribute__((ext_vector_type(8))) short bf16x8;

__device__ __forceinline__ unsigned short f2b(float f){
    union { float f; unsigned u; } x; x.f = f;
    return (unsigned short)((x.u + 0x7FFFu + ((x.u >> 16) & 1u)) >> 16);
}
__device__ __forceinline__ float b2f(unsigned short s){
    union { unsigned u; float f; } x; x.u = ((unsigned)s) << 16;
    return x.f;
}
__device__ __forceinline__ bf16x8 lds8(const unsigned short* p){
    union { uint4 u; bf16x8 v; } t; t.u = *(const uint4*)p; return t.v;
}
__device__ __forceinline__ void glds16(const void* g, void* l){
    __builtin_amdgcn_global_load_lds((const __attribute__((address_space(1))) unsigned*)g,
                                     (__attribute__((address_space(3))) unsigned*)l, 16, 0, 0);
}

// fp32 -> bf16 convert, 8 elems/thread
__global__ __launch_bounds__(256) void cvt_kernel(const float* __restrict__ in,
                                                  unsigned short* __restrict__ out, int n)
{
    int i = (blockIdx.x * 256 + threadIdx.x) * 8;
    if (i >= n) return;
    float4 a = *(const float4*)(in + i);
    float4 b = *(const float4*)(in + i + 4);
    union { unsigned short u[8]; uint4 v; } t;
    t.u[0]=f2b(a.x); t.u[1]=f2b(a.y); t.u[2]=f2b(a.z); t.u[3]=f2b(a.w);
    t.u[4]=f2b(b.x); t.u[5]=f2b(b.y); t.u[6]=f2b(b.z); t.u[7]=f2b(b.w);
    *(uint4*)(out + i) = t.v;
}

// ===== 256x256 GEMM, BK=32, 4-buffer LDS ring, counted vmcnt (T4) =====
// C[M x Nn] = A[M x 1024]_bf16 * Bw[Nn x 1024]_bf16^T + bias.
// 512 threads = 8 waves (2M x 4N), per-wave 128x64 out. LDS 128KiB = 4 bufs
// x (A 16KB + B 16KB). Prefetch distance 2; steady-state wait = vmcnt(8).
// Swizzle: LDS [row][seg] holds global seg ^ (row&3) (seg = 8 shorts).
template<bool OUT_BF16>
__global__ __launch_bounds__(512, 2) void gemm256(const unsigned short* __restrict__ A,
        const unsigned short* __restrict__ Bw, const float* __restrict__ bias,
        void* __restrict__ Cp, int Nn)
{
    extern __shared__ unsigned short sm[];
    unsigned short* As = sm;            // [4][256][32] shorts
    unsigned short* Bs = sm + 32768;

    const int tid = threadIdx.x, lane = tid & 63;
    const int w = tid >> 6, wm = w >> 2, wn = w & 3;
    const int rl = lane & 15, kslot = lane >> 4;

    // T1: bijective XCD swizzle (nwg % 8 == 0 for both GEMMs)
    const int gx = gridDim.x;
    const int nwg = gx * gridDim.y;
    int id = blockIdx.y * gx + blockIdx.x;
    id = (id & 7) * (nwg >> 3) + (id >> 3);
    const int cBase = (id % gx) * 256;
    const int mBase = (id / gx) * 256;

    // staging: load j covers row = j*128 + tid>>2, seg = tid&3 (16B each).
    // source seg pre-swizzled: seg ^ (row&3); row&3 == (tid>>2)&3 for all j.
    const int srow = tid >> 2;
    const int sseg = ((tid & 3) ^ ((tid >> 2) & 3)) * 8;
    const unsigned short* Ag = A  + (size_t)(mBase + srow) * KD + sseg;
    const unsigned short* Bg = Bw + (size_t)(cBase + srow) * KD + sseg;

    // fragment read offsets (shorts), physical seg = kslot ^ (rl&3)
    const int psg = (kslot ^ (rl & 3)) * 8;
    const int aoff = (wm * 128 + rl) * 32 + psg;   // + m*512 per m-frag
    const int boff = (wn * 64  + rl) * 32 + psg;   // + n*512 per n-frag

    f32x4 acc[8][4];
    #pragma unroll
    for (int m = 0; m < 8; m++)
        #pragma unroll
        for (int n = 0; n < 4; n++) acc[m][n] = (f32x4)0.f;

#define STAGE(bb, kk) { \
        glds16(Ag + (kk),            As + (bb)*8192 + tid*8); \
        glds16(Ag + 128*KD + (kk),   As + (bb)*8192 + 4096 + tid*8); \
        glds16(Bg + (kk),            Bs + (bb)*8192 + tid*8); \
        glds16(Bg + 128*KD + (kk),   Bs + (bb)*8192 + 4096 + tid*8); }

#define DSREAD(bb) { \
        const unsigned short* a_ = As + (bb)*8192; \
        const unsigned short* b_ = Bs + (bb)*8192; \
        _Pragma("unroll") \
        for (int m = 0; m < 8; m++) af[m] = lds8(a_ + aoff + m * 512); \
        _Pragma("unroll") \
        for (int n = 0; n < 4; n++) bf[n] = lds8(b_ + boff + n * 512); }

#define MFMA32() { \
        __builtin_amdgcn_s_setprio(1); \
        _Pragma("unroll") \
        for (int m = 0; m < 8; m++) \
            _Pragma("unroll") \
            for (int n = 0; n < 4; n++) \
                acc[m][n] = __builtin_amdgcn_mfma_f32_16x16x32_bf16(af[m], bf[n], acc[m][n], 0, 0, 0); \
        __builtin_amdgcn_s_setprio(0); }

    bf16x8 af[8], bf[4];

    STAGE(0, 0)
    STAGE(1, 32)

    for (int t = 0; t < 30; ++t) {
        STAGE((t + 2) & 3, (t + 2) * 32)
        asm volatile("s_waitcnt vmcnt(8)" ::: "memory");   // stage(t) landed
        __builtin_amdgcn_s_barrier();                      // all waves agree
        DSREAD(t & 3)
        __builtin_amdgcn_s_barrier();
        asm volatile("s_waitcnt lgkmcnt(0)" ::: "memory");
        __builtin_amdgcn_sched_barrier(0);
        MFMA32()
    }
    // tail t=30
    asm volatile("s_waitcnt vmcnt(4)" ::: "memory");
    __builtin_amdgcn_s_barrier();
    DSREAD(2)
    __builtin_amdgcn_s_barrier();
    asm volatile("s_waitcnt lgkmcnt(0)" ::: "memory");
    __builtin_amdgcn_sched_barrier(0);
    MFMA32()
    // tail t=31
    asm volatile("s_waitcnt vmcnt(0)" ::: "memory");
    __builtin_amdgcn_s_barrier();
    DSREAD(3)
    asm volatile("s_waitcnt lgkmcnt(0)" ::: "memory");
    __builtin_amdgcn_sched_barrier(0);
    MFMA32()
#undef STAGE
#undef DSREAD
#undef MFMA32

    // epilogue: C/D layout col=lane&15, row=(lane>>4)*4+reg.
    // n-inner store order: 4 back-to-back stores fill each 128B row segment
    // (L2 sector merge; avoids 64B partial-line write amplification).
    float bv[4];
    #pragma unroll
    for (int n = 0; n < 4; n++) bv[n] = bias[cBase + wn * 64 + n * 16 + rl];
    #pragma unroll
    for (int m = 0; m < 8; m++) {
        #pragma unroll
        for (int i = 0; i < 4; i++) {
            const size_t row = mBase + wm * 128 + m * 16 + kslot * 4 + i;
            #pragma unroll
            for (int n = 0; n < 4; n++) {
                const int col = cBase + wn * 64 + n * 16 + rl;
                const float val = acc[m][n][i] + bv[n];
                if (OUT_BF16) ((unsigned short*)Cp)[row * Nn + col] = f2b(val);
                else          ((float*)Cp)[row * Nn + col] = val;
            }
        }
    }
}

// Per-token head-attention. One wave per token, 4 tokens/block.
__global__ __launch_bounds__(256) void attn_kernel(const unsigned short* __restrict__ qkv,
                                                   unsigned short* __restrict__ outp)
{
    __shared__ __align__(16) unsigned short qs[4][48 * 72];
    __shared__ float ps[4][16 * 17];
    const int tid = threadIdx.x, w = tid >> 6, lane = tid & 63;
    const int t = blockIdx.x * 4 + w;

    const unsigned short* src = qkv + (size_t)t * NQKV;
    #pragma unroll
    for (int i = 0; i < 6; i++) {
        const int e = i * 512 + lane * 8;
        uint4 v = *(const uint4*)(src + e);
        *(uint4*)&qs[w][(e >> 6) * 72 + (e & 63)] = v;
    }
    __syncthreads();

    const int h = lane & 15, g0 = lane >> 4;
    uint4 qv[8];
    #pragma unroll
    for (int i = 0; i < 8; i++) qv[i] = *(const uint4*)&qs[w][h * 72 + i * 8];
    float s[4];
    #pragma unroll
    for (int i = 0; i < 4; i++) {
        const int g = g0 * 4 + i;
        float a = 0.f;
        #pragma unroll
        for (int c = 0; c < 8; c++) {
            uint4 kv = *(const uint4*)&qs[w][(16 + g) * 72 + c * 8];
            uint qa[4] = {qv[c].x, qv[c].y, qv[c].z, qv[c].w};
            uint ka[4] = {kv.x, kv.y, kv.z, kv.w};
            #pragma unroll
            for (int u = 0; u < 4; u++) {
                a += b2f((unsigned short)qa[u]) * b2f((unsigned short)ka[u]);
                a += b2f((unsigned short)(qa[u] >> 16)) * b2f((unsigned short)(ka[u] >> 16));
            }
        }
        s[i] = a * ATT_SCALE;
    }
    float mx = fmaxf(fmaxf(s[0], s[1]), fmaxf(s[2], s[3]));
    mx = fmaxf(mx, __shfl_xor(mx, 16, 64));
    mx = fmaxf(mx, __shfl_xor(mx, 32, 64));
    float p[4], smv = 0.f;
    #pragma unroll
    for (int i = 0; i < 4; i++) { p[i] = __expf(s[i] - mx); smv += p[i]; }
    smv += __shfl_xor(smv, 16, 64);
    smv += __shfl_xor(smv, 32, 64);
    const float inv = 1.f / smv;
    #pragma unroll
    for (int i = 0; i < 4; i++) ps[w][h * 17 + g0 * 4 + i] = p[i] * inv;
    __syncthreads();

    const int h2 = lane >> 2, db = (lane & 3) * 16;
    float pr[16];
    #pragma unroll
    for (int g = 0; g < 16; g++) pr[g] = ps[w][h2 * 17 + g];
    float acc[16];
    #pragma unroll
    for (int j = 0; j < 16; j++) acc[j] = 0.f;
    #pragma unroll
    for (int g = 0; g < 16; g++) {
        const unsigned short* vp = &qs[w][(32 + g) * 72 + db];
        uint4 v0 = *(const uint4*)vp;
        uint4 v1 = *(const uint4*)(vp + 8);
        const float pg = pr[g];
        uint va[8] = {v0.x, v0.y, v0.z, v0.w, v1.x, v1.y, v1.z, v1.w};
        #pragma unroll
        for (int u = 0; u < 8; u++) {
            acc[2*u]   += pg * b2f((unsigned short)va[u]);
            acc[2*u+1] += pg * b2f((unsigned short)(va[u] >> 16));
        }
    }
    const int b = t >> 12, n = t & 4095;
    const int n1 = h2 * 256 + (n >> 4);
    const int c0 = (n & 15) * 64 + db;
    union { unsigned short u[16]; uint4 v[2]; } st;
    #pragma unroll
    for (int j = 0; j < 16; j++) st.u[j] = f2b(acc[j]);
    unsigned short* dst = outp + ((size_t)(b * SEQL + n1)) * 1024 + c0;
    *(uint4*)dst       = st.v[0];
    *(uint4*)(dst + 8) = st.v[1];
}

extern "C" void kernel_launch(void* const* d_in, const int* in_sizes, int n_in,
                              void* d_out, int out_size, void* d_ws, size_t ws_size,
                              hipStream_t stream)
{
    const float* x      = (const float*)d_in[0];
    const float* qkv_w  = (const float*)d_in[1];
    const float* qkv_b  = (const float*)d_in[2];
    const float* proj_w = (const float*)d_in[3];
    const float* proj_b = (const float*)d_in[4];

    unsigned short* xb  = (unsigned short*)d_ws;            // 33.5 MB
    unsigned short* qkv = xb + (size_t)TOK * KD;            // 100.7 MB
    unsigned short* qwb = qkv + (size_t)TOK * NQKV;         // 6.3 MB
    unsigned short* pwb = qwb + (size_t)NQKV * KD;          // 2.1 MB
    unsigned short* att = xb;                               // alias (after QKV GEMM)

    hipFuncSetAttribute(reinterpret_cast<const void*>(&gemm256<true>),
                        hipFuncAttributeMaxDynamicSharedMemorySize, 131072);
    hipFuncSetAttribute(reinterpret_cast<const void*>(&gemm256<false>),
                        hipFuncAttributeMaxDynamicSharedMemorySize, 131072);

    cvt_kernel<<<dim3(TOK * KD / 2048), dim3(256), 0, stream>>>(x, xb, TOK * KD);
    cvt_kernel<<<dim3(NQKV * KD / 2048), dim3(256), 0, stream>>>(qkv_w, qwb, NQKV * KD);
    cvt_kernel<<<dim3(KD * KD / 2048), dim3(256), 0, stream>>>(proj_w, pwb, KD * KD);

    gemm256<true><<<dim3(NQKV / 256, TOK / 256), dim3(512), 131072, stream>>>(
        xb, qwb, qkv_b, qkv, NQKV);
    attn_kernel<<<dim3(TOK / 4), dim3(256), 0, stream>>>(qkv, att);
    gemm256<false><<<dim3(KD / 256, TOK / 256), dim3(512), 131072, stream>>>(
        att, pwb, proj_b, (float*)d_out, KD);
}

// Round 5
// 201.079 us; speedup vs baseline: 1.1346x; 1.1346x over previous
//
#include <hip/hip_runtime.h>
#include <hip/hip_bf16.h>

#define TOK   16384       // B*N = 4*4096
#define KD    1024        // DIM
#define NQKV  3072
#define SEQL  4096
#define ATT_SCALE 0.125f  // 64^-0.5

typedef __attribute__((ext_vector_type(4))) float f32x4;
typedef __attribute__((ext_vector_type(8))) short bf16x8;

__device__ __forceinline__ unsigned short f2b(float f){
    union { float f; unsigned u; } x; x.f = f;
    return (unsigned short)((x.u + 0x7FFFu + ((x.u >> 16) & 1u)) >> 16);
}
__device__ __forceinline__ float b2f(unsigned short s){
    union { unsigned u; float f; } x; x.u = ((unsigned)s) << 16;
    return x.f;
}
__device__ __forceinline__ bf16x8 lds8(const unsigned short* p){
    union { uint4 u; bf16x8 v; } t; t.u = *(const uint4*)p; return t.v;
}
__device__ __forceinline__ void glds16(const void* g, void* l){
    __builtin_amdgcn_global_load_lds((const __attribute__((address_space(1))) unsigned*)g,
                                     (__attribute__((address_space(3))) unsigned*)l, 16, 0, 0);
}

// fp32 -> bf16 convert, 8 elems/thread
__global__ __launch_bounds__(256) void cvt_kernel(const float* __restrict__ in,
                                                  unsigned short* __restrict__ out, int n)
{
    int i = (blockIdx.x * 256 + threadIdx.x) * 8;
    if (i >= n) return;
    float4 a = *(const float4*)(in + i);
    float4 b = *(const float4*)(in + i + 4);
    union { unsigned short u[8]; uint4 v; } t;
    t.u[0]=f2b(a.x); t.u[1]=f2b(a.y); t.u[2]=f2b(a.z); t.u[3]=f2b(a.w);
    t.u[4]=f2b(b.x); t.u[5]=f2b(b.y); t.u[6]=f2b(b.z); t.u[7]=f2b(b.w);
    *(uint4*)(out + i) = t.v;
}

// ===== 256x256 GEMM, BK=64, 4 quadrant-phases/tile, counted vmcnt(6) =====
// C[M x Nn] = A[M x 1024]_bf16 * Bw[Nn x 1024]_bf16^T + bias.
// 512 threads = 8 waves (2M x 4N). Half-tile (128 rows x 64 cols = 2 glds)
// staged per phase, 3 half-tiles always in flight (vmcnt(6), never 0 until
// the last tile). Fragment->row maps chosen so each half-tile is FIRST
// needed at a distinct phase:
//   A-frag m -> row (m>>2)*128 + (m&3)*32 + wm*16 + rl   (P0: rows 0-127)
//   B LDS row n*64+wn*16+rl holds global col wn*64+n*16+rl (P0: rows 0-127)
// Swizzle (r3, conflict-free): LDS seg s holds global seg s ^ (row&7).
template<bool OUT_BF16>
__global__ __launch_bounds__(512, 2) void gemm256(const unsigned short* __restrict__ A,
        const unsigned short* __restrict__ Bw, const float* __restrict__ bias,
        void* __restrict__ Cp, int Nn)
{
    extern __shared__ unsigned short smem[];
    unsigned short* As = smem;            // [2][256][64] shorts
    unsigned short* Bs = smem + 32768;

    const int tid = threadIdx.x, lane = tid & 63;
    const int w = tid >> 6, wm = w >> 2, wn = w & 3;
    const int rl = lane & 15, kslot = lane >> 4;

    // T1: bijective XCD swizzle (nwg % 8 == 0 for both GEMMs)
    const int gx = gridDim.x;
    const int nwg = gx * gridDim.y;
    int id = blockIdx.y * gx + blockIdx.x;
    id = (id & 7) * (nwg >> 3) + (id >> 3);
    const int cBase = (id % gx) * 256;
    const int mBase = (id / gx) * 256;

    // staging: thread covers LDS row u (per 64-row chunk), seg tid&7;
    // global source seg pre-swizzled with (LDS row)&7 = u&7.
    const int u = tid >> 3;
    const int seg8 = ((tid & 7) ^ (u & 7)) * 8;
    const unsigned short* Ag = A  + (size_t)(mBase + u) * KD + seg8;                      // chunk k: +k*64*KD
    const unsigned short* Bg = Bw + (size_t)(cBase + (u >> 4) * 64 + (u & 15)) * KD + seg8; // chunk k: +k*16*KD

    // fragment read offsets (shorts)
    const int arow = (wm * 16 + rl) * 64;      // + m*2048 (+8192 for m4-7)
    const int brow = (wn * 16 + rl) * 64;      // + n*4096
    const int psg0 = (kslot ^ (rl & 7)) * 8;          // ks=0
    const int psg1 = ((kslot + 4) ^ (rl & 7)) * 8;    // ks=1

    f32x4 acc[8][4];
    #pragma unroll
    for (int m = 0; m < 8; m++)
        #pragma unroll
        for (int n = 0; n < 4; n++) acc[m][n] = (f32x4)0.f;

#define STAGE_AH0(bb, kk) { glds16(Ag + (kk),            As + (bb)*16384 + tid*8); \
                            glds16(Ag + 64*KD + (kk),    As + (bb)*16384 + 4096  + tid*8); }
#define STAGE_AH1(bb, kk) { glds16(Ag + 128*KD + (kk),   As + (bb)*16384 + 8192  + tid*8); \
                            glds16(Ag + 192*KD + (kk),   As + (bb)*16384 + 12288 + tid*8); }
#define STAGE_BH0(bb, kk) { glds16(Bg + (kk),            Bs + (bb)*16384 + tid*8); \
                            glds16(Bg + 16*KD + (kk),    Bs + (bb)*16384 + 4096  + tid*8); }
#define STAGE_BH1(bb, kk) { glds16(Bg + 32*KD + (kk),    Bs + (bb)*16384 + 8192  + tid*8); \
                            glds16(Bg + 48*KD + (kk),    Bs + (bb)*16384 + 12288 + tid*8); }

#define RDA(a_, half) { _Pragma("unroll") \
    for (int m = 0; m < 4; m++) { \
        af[m][0] = lds8((a_) + (half)*8192 + arow + m*2048 + psg0); \
        af[m][1] = lds8((a_) + (half)*8192 + arow + m*2048 + psg1); } }
#define RDB(b_, nlo) { _Pragma("unroll") \
    for (int n = 0; n < 2; n++) { \
        bf[(nlo)+n][0] = lds8((b_) + brow + ((nlo)+n)*4096 + psg0); \
        bf[(nlo)+n][1] = lds8((b_) + brow + ((nlo)+n)*4096 + psg1); } }

#define MM16(mb, nb) { \
    __builtin_amdgcn_s_setprio(1); \
    _Pragma("unroll") \
    for (int m = 0; m < 4; m++) \
        _Pragma("unroll") \
        for (int n = 0; n < 2; n++) { \
            acc[(mb)+m][(nb)+n] = __builtin_amdgcn_mfma_f32_16x16x32_bf16(af[m][0], bf[(nb)+n][0], acc[(mb)+m][(nb)+n], 0, 0, 0); \
            acc[(mb)+m][(nb)+n] = __builtin_amdgcn_mfma_f32_16x16x32_bf16(af[m][1], bf[(nb)+n][1], acc[(mb)+m][(nb)+n], 0, 0, 0); } \
    __builtin_amdgcn_s_setprio(0); }

#define WAITLGKM { asm volatile("s_waitcnt lgkmcnt(0)" ::: "memory"); __builtin_amdgcn_sched_barrier(0); }

    bf16x8 af[4][2], bf[4][2];

    // prologue: tile 0 -> buf 0 (8 loads)
    STAGE_AH0(0, 0)
    STAGE_BH0(0, 0)
    STAGE_BH1(0, 0)
    STAGE_AH1(0, 0)

    int buf = 0;
    for (int t = 0; t < 15; ++t) {
        const unsigned short* a = As + buf * 16384;
        const unsigned short* b = Bs + buf * 16384;
        const int nk = (t + 1) * 64;
        // P0: needs Ah0(t), Bh0(t); leaves Bh1(t),Ah1(t),Ah0(t+1) in flight
        STAGE_AH0(buf ^ 1, nk)
        asm volatile("s_waitcnt vmcnt(6)" ::: "memory");
        __builtin_amdgcn_s_barrier();
        RDA(a, 0) RDB(b, 0)
        WAITLGKM
        MM16(0, 0)
        // P1: needs Bh1(t)
        STAGE_BH0(buf ^ 1, nk)
        asm volatile("s_waitcnt vmcnt(6)" ::: "memory");
        __builtin_amdgcn_s_barrier();
        RDB(b, 2)
        WAITLGKM
        MM16(0, 2)
        // P2: needs Ah1(t)
        STAGE_BH1(buf ^ 1, nk)
        asm volatile("s_waitcnt vmcnt(6)" ::: "memory");
        __builtin_amdgcn_s_barrier();
        RDA(a, 1)
        WAITLGKM
        MM16(4, 0)
        // P3: register-only
        STAGE_AH1(buf ^ 1, nk)
        MM16(4, 2)
        buf ^= 1;
    }
    // tail tile 15 (no staging; counted drain 4 -> 2 -> 0)
    {
        const unsigned short* a = As + buf * 16384;
        const unsigned short* b = Bs + buf * 16384;
        asm volatile("s_waitcnt vmcnt(4)" ::: "memory");
        __builtin_amdgcn_s_barrier();
        RDA(a, 0) RDB(b, 0)
        WAITLGKM
        MM16(0, 0)
        asm volatile("s_waitcnt vmcnt(2)" ::: "memory");
        __builtin_amdgcn_s_barrier();
        RDB(b, 2)
        WAITLGKM
        MM16(0, 2)
        asm volatile("s_waitcnt vmcnt(0)" ::: "memory");
        __builtin_amdgcn_s_barrier();
        RDA(a, 1)
        WAITLGKM
        MM16(4, 0)
        MM16(4, 2)
    }
#undef STAGE_AH0
#undef STAGE_AH1
#undef STAGE_BH0
#undef STAGE_BH1
#undef RDA
#undef RDB
#undef MM16
#undef WAITLGKM

    // epilogue: C/D layout col=lane&15, row=(lane>>4)*4+reg.
    // row map: mBase + (m>>2)*128 + (m&3)*32 + wm*16 + kslot*4 + i
    // col map: cBase + wn*64 + n*16 + rl  (n-inner -> 128B contiguous/wave)
    float bv[4];
    #pragma unroll
    for (int n = 0; n < 4; n++) bv[n] = bias[cBase + wn * 64 + n * 16 + rl];
    #pragma unroll
    for (int m = 0; m < 8; m++) {
        #pragma unroll
        for (int i = 0; i < 4; i++) {
            const size_t row = mBase + (m >> 2) * 128 + (m & 3) * 32 + wm * 16 + kslot * 4 + i;
            #pragma unroll
            for (int n = 0; n < 4; n++) {
                const int col = cBase + wn * 64 + n * 16 + rl;
                const float val = acc[m][n][i] + bv[n];
                if (OUT_BF16) ((unsigned short*)Cp)[row * Nn + col] = f2b(val);
                else          ((float*)Cp)[row * Nn + col] = val;
            }
        }
    }
}

// Per-token head-attention. One wave per token, 4 tokens/block.
__global__ __launch_bounds__(256) void attn_kernel(const unsigned short* __restrict__ qkv,
                                                   unsigned short* __restrict__ outp)
{
    __shared__ __align__(16) unsigned short qs[4][48 * 72];
    __shared__ float ps[4][16 * 17];
    const int tid = threadIdx.x, w = tid >> 6, lane = tid & 63;
    const int t = blockIdx.x * 4 + w;

    const unsigned short* src = qkv + (size_t)t * NQKV;
    #pragma unroll
    for (int i = 0; i < 6; i++) {
        const int e = i * 512 + lane * 8;
        uint4 v = *(const uint4*)(src + e);
        *(uint4*)&qs[w][(e >> 6) * 72 + (e & 63)] = v;
    }
    __syncthreads();

    const int h = lane & 15, g0 = lane >> 4;
    uint4 qv[8];
    #pragma unroll
    for (int i = 0; i < 8; i++) qv[i] = *(const uint4*)&qs[w][h * 72 + i * 8];
    float s[4];
    #pragma unroll
    for (int i = 0; i < 4; i++) {
        const int g = g0 * 4 + i;
        float a = 0.f;
        #pragma unroll
        for (int c = 0; c < 8; c++) {
            uint4 kv = *(const uint4*)&qs[w][(16 + g) * 72 + c * 8];
            uint qa[4] = {qv[c].x, qv[c].y, qv[c].z, qv[c].w};
            uint ka[4] = {kv.x, kv.y, kv.z, kv.w};
            #pragma unroll
            for (int uu = 0; uu < 4; uu++) {
                a += b2f((unsigned short)qa[uu]) * b2f((unsigned short)ka[uu]);
                a += b2f((unsigned short)(qa[uu] >> 16)) * b2f((unsigned short)(ka[uu] >> 16));
            }
        }
        s[i] = a * ATT_SCALE;
    }
    float mx = fmaxf(fmaxf(s[0], s[1]), fmaxf(s[2], s[3]));
    mx = fmaxf(mx, __shfl_xor(mx, 16, 64));
    mx = fmaxf(mx, __shfl_xor(mx, 32, 64));
    float p[4], smv = 0.f;
    #pragma unroll
    for (int i = 0; i < 4; i++) { p[i] = __expf(s[i] - mx); smv += p[i]; }
    smv += __shfl_xor(smv, 16, 64);
    smv += __shfl_xor(smv, 32, 64);
    const float inv = 1.f / smv;
    #pragma unroll
    for (int i = 0; i < 4; i++) ps[w][h * 17 + g0 * 4 + i] = p[i] * inv;
    __syncthreads();

    const int h2 = lane >> 2, db = (lane & 3) * 16;
    float pr[16];
    #pragma unroll
    for (int g = 0; g < 16; g++) pr[g] = ps[w][h2 * 17 + g];
    float acc[16];
    #pragma unroll
    for (int j = 0; j < 16; j++) acc[j] = 0.f;
    #pragma unroll
    for (int g = 0; g < 16; g++) {
        const unsigned short* vp = &qs[w][(32 + g) * 72 + db];
        uint4 v0 = *(const uint4*)vp;
        uint4 v1 = *(const uint4*)(vp + 8);
        const float pg = pr[g];
        uint va[8] = {v0.x, v0.y, v0.z, v0.w, v1.x, v1.y, v1.z, v1.w};
        #pragma unroll
        for (int uu = 0; uu < 8; uu++) {
            acc[2*uu]   += pg * b2f((unsigned short)va[uu]);
            acc[2*uu+1] += pg * b2f((unsigned short)(va[uu] >> 16));
        }
    }
    const int b = t >> 12, n = t & 4095;
    const int n1 = h2 * 256 + (n >> 4);
    const int c0 = (n & 15) * 64 + db;
    union { unsigned short u[16]; uint4 v[2]; } st;
    #pragma unroll
    for (int j = 0; j < 16; j++) st.u[j] = f2b(acc[j]);
    unsigned short* dst = outp + ((size_t)(b * SEQL + n1)) * 1024 + c0;
    *(uint4*)dst       = st.v[0];
    *(uint4*)(dst + 8) = st.v[1];
}

extern "C" void kernel_launch(void* const* d_in, const int* in_sizes, int n_in,
                              void* d_out, int out_size, void* d_ws, size_t ws_size,
                              hipStream_t stream)
{
    const float* x      = (const float*)d_in[0];
    const float* qkv_w  = (const float*)d_in[1];
    const float* qkv_b  = (const float*)d_in[2];
    const float* proj_w = (const float*)d_in[3];
    const float* proj_b = (const float*)d_in[4];

    unsigned short* xb  = (unsigned short*)d_ws;            // 33.5 MB
    unsigned short* qkv = xb + (size_t)TOK * KD;            // 100.7 MB
    unsigned short* qwb = qkv + (size_t)TOK * NQKV;         // 6.3 MB
    unsigned short* pwb = qwb + (size_t)NQKV * KD;          // 2.1 MB
    unsigned short* att = xb;                               // alias (after QKV GEMM)

    hipFuncSetAttribute(reinterpret_cast<const void*>(&gemm256<true>),
                        hipFuncAttributeMaxDynamicSharedMemorySize, 131072);
    hipFuncSetAttribute(reinterpret_cast<const void*>(&gemm256<false>),
                        hipFuncAttributeMaxDynamicSharedMemorySize, 131072);

    cvt_kernel<<<dim3(TOK * KD / 2048), dim3(256), 0, stream>>>(x, xb, TOK * KD);
    cvt_kernel<<<dim3(NQKV * KD / 2048), dim3(256), 0, stream>>>(qkv_w, qwb, NQKV * KD);
    cvt_kernel<<<dim3(KD * KD / 2048), dim3(256), 0, stream>>>(proj_w, pwb, KD * KD);

    gemm256<true><<<dim3(NQKV / 256, TOK / 256), dim3(512), 131072, stream>>>(
        xb, qwb, qkv_b, qkv, NQKV);
    attn_kernel<<<dim3(TOK / 4), dim3(256), 0, stream>>>(qkv, att);
    gemm256<false><<<dim3(KD / 256, TOK / 256), dim3(512), 131072, stream>>>(
        att, pwb, proj_b, (float*)d_out, KD);
}

// Round 6
// 199.467 us; speedup vs baseline: 1.1438x; 1.0081x over previous
//
#include <hip/hip_runtime.h>
#include <hip/hip_bf16.h>

#define TOK   16384       // B*N = 4*4096
#define KD    1024        // DIM
#define NQKV  3072
#define SEQL  4096
#define ATT_SCALE 0.125f  // 64^-0.5

typedef __attribute__((ext_vector_type(4))) float f32x4;
typedef __attribute__((ext_vector_type(8))) short bf16x8;

__device__ __forceinline__ unsigned short f2b(float f){
    union { float f; unsigned u; } x; x.f = f;
    return (unsigned short)((x.u + 0x7FFFu + ((x.u >> 16) & 1u)) >> 16);
}
__device__ __forceinline__ float b2f(unsigned short s){
    union { unsigned u; float f; } x; x.u = ((unsigned)s) << 16;
    return x.f;
}
__device__ __forceinline__ bf16x8 lds8(const unsigned short* p){
    union { uint4 u; bf16x8 v; } t; t.u = *(const uint4*)p; return t.v;
}
__device__ __forceinline__ void glds16(const void* g, void* l){
    __builtin_amdgcn_global_load_lds((const __attribute__((address_space(1))) unsigned*)g,
                                     (__attribute__((address_space(3))) unsigned*)l, 16, 0, 0);
}

// fp32 -> bf16 convert, 8 elems/thread
__global__ __launch_bounds__(256) void cvt_kernel(const float* __restrict__ in,
                                                  unsigned short* __restrict__ out, int n)
{
    int i = (blockIdx.x * 256 + threadIdx.x) * 8;
    if (i >= n) return;
    float4 a = *(const float4*)(in + i);
    float4 b = *(const float4*)(in + i + 4);
    union { unsigned short u[8]; uint4 v; } t;
    t.u[0]=f2b(a.x); t.u[1]=f2b(a.y); t.u[2]=f2b(a.z); t.u[3]=f2b(a.w);
    t.u[4]=f2b(b.x); t.u[5]=f2b(b.y); t.u[6]=f2b(b.z); t.u[7]=f2b(b.w);
    *(uint4*)(out + i) = t.v;
}

// ===== 256x256 GEMM, BK=64, 4 quadrant-phases/tile, counted vmcnt(6) =====
// Same as r5 EXCEPT: no forced lgkmcnt(0)/sched_barrier between ds_read and
// MFMA — the compiler emits fine-grained counted lgkmcnt and interleaves
// ds_read issue with MFMA issue inside each phase (m97/m141 evidence).
template<bool OUT_BF16>
__global__ __launch_bounds__(512, 2) void gemm256(const unsigned short* __restrict__ A,
        const unsigned short* __restrict__ Bw, const float* __restrict__ bias,
        void* __restrict__ Cp, int Nn)
{
    extern __shared__ unsigned short smem[];
    unsigned short* As = smem;            // [2][256][64] shorts
    unsigned short* Bs = smem + 32768;

    const int tid = threadIdx.x, lane = tid & 63;
    const int w = tid >> 6, wm = w >> 2, wn = w & 3;
    const int rl = lane & 15, kslot = lane >> 4;

    // T1: bijective XCD swizzle (nwg % 8 == 0 for both GEMMs)
    const int gx = gridDim.x;
    const int nwg = gx * gridDim.y;
    int id = blockIdx.y * gx + blockIdx.x;
    id = (id & 7) * (nwg >> 3) + (id >> 3);
    const int cBase = (id % gx) * 256;
    const int mBase = (id / gx) * 256;

    // staging: thread covers LDS row u (per 64-row chunk), seg tid&7;
    // global source seg pre-swizzled with (LDS row)&7 = u&7.
    const int u = tid >> 3;
    const int seg8 = ((tid & 7) ^ (u & 7)) * 8;
    const unsigned short* Ag = A  + (size_t)(mBase + u) * KD + seg8;                      // chunk k: +k*64*KD
    const unsigned short* Bg = Bw + (size_t)(cBase + (u >> 4) * 64 + (u & 15)) * KD + seg8; // chunk k: +k*16*KD

    // fragment read offsets (shorts)
    const int arow = (wm * 16 + rl) * 64;      // + m*2048 (+8192 for m4-7)
    const int brow = (wn * 16 + rl) * 64;      // + n*4096
    const int psg0 = (kslot ^ (rl & 7)) * 8;          // ks=0
    const int psg1 = ((kslot + 4) ^ (rl & 7)) * 8;    // ks=1

    f32x4 acc[8][4];
    #pragma unroll
    for (int m = 0; m < 8; m++)
        #pragma unroll
        for (int n = 0; n < 4; n++) acc[m][n] = (f32x4)0.f;

#define STAGE_AH0(bb, kk) { glds16(Ag + (kk),            As + (bb)*16384 + tid*8); \
                            glds16(Ag + 64*KD + (kk),    As + (bb)*16384 + 4096  + tid*8); }
#define STAGE_AH1(bb, kk) { glds16(Ag + 128*KD + (kk),   As + (bb)*16384 + 8192  + tid*8); \
                            glds16(Ag + 192*KD + (kk),   As + (bb)*16384 + 12288 + tid*8); }
#define STAGE_BH0(bb, kk) { glds16(Bg + (kk),            Bs + (bb)*16384 + tid*8); \
                            glds16(Bg + 16*KD + (kk),    Bs + (bb)*16384 + 4096  + tid*8); }
#define STAGE_BH1(bb, kk) { glds16(Bg + 32*KD + (kk),    Bs + (bb)*16384 + 8192  + tid*8); \
                            glds16(Bg + 48*KD + (kk),    Bs + (bb)*16384 + 12288 + tid*8); }

#define RDA(a_, half) { _Pragma("unroll") \
    for (int m = 0; m < 4; m++) { \
        af[m][0] = lds8((a_) + (half)*8192 + arow + m*2048 + psg0); \
        af[m][1] = lds8((a_) + (half)*8192 + arow + m*2048 + psg1); } }
#define RDB(b_, nlo) { _Pragma("unroll") \
    for (int n = 0; n < 2; n++) { \
        bf[(nlo)+n][0] = lds8((b_) + brow + ((nlo)+n)*4096 + psg0); \
        bf[(nlo)+n][1] = lds8((b_) + brow + ((nlo)+n)*4096 + psg1); } }

#define MM16(mb, nb) { \
    _Pragma("unroll") \
    for (int m = 0; m < 4; m++) \
        _Pragma("unroll") \
        for (int n = 0; n < 2; n++) { \
            acc[(mb)+m][(nb)+n] = __builtin_amdgcn_mfma_f32_16x16x32_bf16(af[m][0], bf[(nb)+n][0], acc[(mb)+m][(nb)+n], 0, 0, 0); \
            acc[(mb)+m][(nb)+n] = __builtin_amdgcn_mfma_f32_16x16x32_bf16(af[m][1], bf[(nb)+n][1], acc[(mb)+m][(nb)+n], 0, 0, 0); } }

    bf16x8 af[4][2], bf[4][2];

    // prologue: tile 0 -> buf 0 (8 loads)
    STAGE_AH0(0, 0)
    STAGE_BH0(0, 0)
    STAGE_BH1(0, 0)
    STAGE_AH1(0, 0)

    int buf = 0;
    for (int t = 0; t < 15; ++t) {
        const unsigned short* a = As + buf * 16384;
        const unsigned short* b = Bs + buf * 16384;
        const int nk = (t + 1) * 64;
        // P0: needs Ah0(t), Bh0(t)
        STAGE_AH0(buf ^ 1, nk)
        asm volatile("s_waitcnt vmcnt(6)" ::: "memory");
        __builtin_amdgcn_s_barrier();
        __builtin_amdgcn_s_setprio(1);
        RDA(a, 0) RDB(b, 0)
        MM16(0, 0)
        __builtin_amdgcn_s_setprio(0);
        // P1: needs Bh1(t)
        STAGE_BH0(buf ^ 1, nk)
        asm volatile("s_waitcnt vmcnt(6)" ::: "memory");
        __builtin_amdgcn_s_barrier();
        __builtin_amdgcn_s_setprio(1);
        RDB(b, 2)
        MM16(0, 2)
        __builtin_amdgcn_s_setprio(0);
        // P2: needs Ah1(t)
        STAGE_BH1(buf ^ 1, nk)
        asm volatile("s_waitcnt vmcnt(6)" ::: "memory");
        __builtin_amdgcn_s_barrier();
        __builtin_amdgcn_s_setprio(1);
        RDA(a, 1)
        MM16(4, 0)
        __builtin_amdgcn_s_setprio(0);
        // P3: register-only
        STAGE_AH1(buf ^ 1, nk)
        __builtin_amdgcn_s_setprio(1);
        MM16(4, 2)
        __builtin_amdgcn_s_setprio(0);
        buf ^= 1;
    }
    // tail tile 15 (no staging; counted drain 4 -> 2 -> 0)
    {
        const unsigned short* a = As + buf * 16384;
        const unsigned short* b = Bs + buf * 16384;
        asm volatile("s_waitcnt vmcnt(4)" ::: "memory");
        __builtin_amdgcn_s_barrier();
        RDA(a, 0) RDB(b, 0)
        MM16(0, 0)
        asm volatile("s_waitcnt vmcnt(2)" ::: "memory");
        __builtin_amdgcn_s_barrier();
        RDB(b, 2)
        MM16(0, 2)
        asm volatile("s_waitcnt vmcnt(0)" ::: "memory");
        __builtin_amdgcn_s_barrier();
        RDA(a, 1)
        MM16(4, 0)
        MM16(4, 2)
    }
#undef STAGE_AH0
#undef STAGE_AH1
#undef STAGE_BH0
#undef STAGE_BH1
#undef RDA
#undef RDB
#undef MM16

    // epilogue: C/D layout col=lane&15, row=(lane>>4)*4+reg.
    // row map: mBase + (m>>2)*128 + (m&3)*32 + wm*16 + kslot*4 + i
    // col map: cBase + wn*64 + n*16 + rl  (n-inner -> 128B contiguous/wave)
    float bv[4];
    #pragma unroll
    for (int n = 0; n < 4; n++) bv[n] = bias[cBase + wn * 64 + n * 16 + rl];
    #pragma unroll
    for (int m = 0; m < 8; m++) {
        #pragma unroll
        for (int i = 0; i < 4; i++) {
            const size_t row = mBase + (m >> 2) * 128 + (m & 3) * 32 + wm * 16 + kslot * 4 + i;
            #pragma unroll
            for (int n = 0; n < 4; n++) {
                const int col = cBase + wn * 64 + n * 16 + rl;
                const float val = acc[m][n][i] + bv[n];
                if (OUT_BF16) ((unsigned short*)Cp)[row * Nn + col] = f2b(val);
                else          ((float*)Cp)[row * Nn + col] = val;
            }
        }
    }
}

// Per-token head-attention. One wave per token, 4 tokens/block.
__global__ __launch_bounds__(256) void attn_kernel(const unsigned short* __restrict__ qkv,
                                                   unsigned short* __restrict__ outp)
{
    __shared__ __align__(16) unsigned short qs[4][48 * 72];
    __shared__ float ps[4][16 * 17];
    const int tid = threadIdx.x, w = tid >> 6, lane = tid & 63;
    const int t = blockIdx.x * 4 + w;

    const unsigned short* src = qkv + (size_t)t * NQKV;
    #pragma unroll
    for (int i = 0; i < 6; i++) {
        const int e = i * 512 + lane * 8;
        uint4 v = *(const uint4*)(src + e);
        *(uint4*)&qs[w][(e >> 6) * 72 + (e & 63)] = v;
    }
    __syncthreads();

    const int h = lane & 15, g0 = lane >> 4;
    uint4 qv[8];
    #pragma unroll
    for (int i = 0; i < 8; i++) qv[i] = *(const uint4*)&qs[w][h * 72 + i * 8];
    float s[4];
    #pragma unroll
    for (int i = 0; i < 4; i++) {
        const int g = g0 * 4 + i;
        float a = 0.f;
        #pragma unroll
        for (int c = 0; c < 8; c++) {
            uint4 kv = *(const uint4*)&qs[w][(16 + g) * 72 + c * 8];
            uint qa[4] = {qv[c].x, qv[c].y, qv[c].z, qv[c].w};
            uint ka[4] = {kv.x, kv.y, kv.z, kv.w};
            #pragma unroll
            for (int uu = 0; uu < 4; uu++) {
                a += b2f((unsigned short)qa[uu]) * b2f((unsigned short)ka[uu]);
                a += b2f((unsigned short)(qa[uu] >> 16)) * b2f((unsigned short)(ka[uu] >> 16));
            }
        }
        s[i] = a * ATT_SCALE;
    }
    float mx = fmaxf(fmaxf(s[0], s[1]), fmaxf(s[2], s[3]));
    mx = fmaxf(mx, __shfl_xor(mx, 16, 64));
    mx = fmaxf(mx, __shfl_xor(mx, 32, 64));
    float p[4], smv = 0.f;
    #pragma unroll
    for (int i = 0; i < 4; i++) { p[i] = __expf(s[i] - mx); smv += p[i]; }
    smv += __shfl_xor(smv, 16, 64);
    smv += __shfl_xor(smv, 32, 64);
    const float inv = 1.f / smv;
    #pragma unroll
    for (int i = 0; i < 4; i++) ps[w][h * 17 + g0 * 4 + i] = p[i] * inv;
    __syncthreads();

    const int h2 = lane >> 2, db = (lane & 3) * 16;
    float pr[16];
    #pragma unroll
    for (int g = 0; g < 16; g++) pr[g] = ps[w][h2 * 17 + g];
    float acc[16];
    #pragma unroll
    for (int j = 0; j < 16; j++) acc[j] = 0.f;
    #pragma unroll
    for (int g = 0; g < 16; g++) {
        const unsigned short* vp = &qs[w][(32 + g) * 72 + db];
        uint4 v0 = *(const uint4*)vp;
        uint4 v1 = *(const uint4*)(vp + 8);
        const float pg = pr[g];
        uint va[8] = {v0.x, v0.y, v0.z, v0.w, v1.x, v1.y, v1.z, v1.w};
        #pragma unroll
        for (int uu = 0; uu < 8; uu++) {
            acc[2*uu]   += pg * b2f((unsigned short)va[uu]);
            acc[2*uu+1] += pg * b2f((unsigned short)(va[uu] >> 16));
        }
    }
    const int b = t >> 12, n = t & 4095;
    const int n1 = h2 * 256 + (n >> 4);
    const int c0 = (n & 15) * 64 + db;
    union { unsigned short u[16]; uint4 v[2]; } st;
    #pragma unroll
    for (int j = 0; j < 16; j++) st.u[j] = f2b(acc[j]);
    unsigned short* dst = outp + ((size_t)(b * SEQL + n1)) * 1024 + c0;
    *(uint4*)dst       = st.v[0];
    *(uint4*)(dst + 8) = st.v[1];
}

extern "C" void kernel_launch(void* const* d_in, const int* in_sizes, int n_in,
                              void* d_out, int out_size, void* d_ws, size_t ws_size,
                              hipStream_t stream)
{
    const float* x      = (const float*)d_in[0];
    const float* qkv_w  = (const float*)d_in[1];
    const float* qkv_b  = (const float*)d_in[2];
    const float* proj_w = (const float*)d_in[3];
    const float* proj_b = (const float*)d_in[4];

    unsigned short* xb  = (unsigned short*)d_ws;            // 33.5 MB
    unsigned short* qkv = xb + (size_t)TOK * KD;            // 100.7 MB
    unsigned short* qwb = qkv + (size_t)TOK * NQKV;         // 6.3 MB
    unsigned short* pwb = qwb + (size_t)NQKV * KD;          // 2.1 MB
    unsigned short* att = xb;                               // alias (after QKV GEMM)

    hipFuncSetAttribute(reinterpret_cast<const void*>(&gemm256<true>),
                        hipFuncAttributeMaxDynamicSharedMemorySize, 131072);
    hipFuncSetAttribute(reinterpret_cast<const void*>(&gemm256<false>),
                        hipFuncAttributeMaxDynamicSharedMemorySize, 131072);

    cvt_kernel<<<dim3(TOK * KD / 2048), dim3(256), 0, stream>>>(x, xb, TOK * KD);
    cvt_kernel<<<dim3(NQKV * KD / 2048), dim3(256), 0, stream>>>(qkv_w, qwb, NQKV * KD);
    cvt_kernel<<<dim3(KD * KD / 2048), dim3(256), 0, stream>>>(proj_w, pwb, KD * KD);

    gemm256<true><<<dim3(NQKV / 256, TOK / 256), dim3(512), 131072, stream>>>(
        xb, qwb, qkv_b, qkv, NQKV);
    attn_kernel<<<dim3(TOK / 4), dim3(256), 0, stream>>>(qkv, att);
    gemm256<false><<<dim3(KD / 256, TOK / 256), dim3(512), 131072, stream>>>(
        att, pwb, proj_b, (float*)d_out, KD);
}